// Round 4
// baseline (268.423 us; speedup 1.0000x reference)
//
#include <hip/hip_runtime.h>
#include <hip/hip_bf16.h>

typedef __hip_bfloat16 bf16;
typedef __attribute__((ext_vector_type(8))) short short8;
typedef __attribute__((ext_vector_type(8))) __bf16 bf16x8;
typedef __attribute__((ext_vector_type(4))) float f32x4;

// MFMA 16x16x32 bf16: a,b are 8 bf16 (4 VGPR), c/d 4 f32.
// C/D: col = lane&15, row = (lane>>4)*4 + reg   [m89/m91]
// A:   lane l holds A[l&15][(l>>4)*8 + j]
// B:   lane l holds B[(l>>4)*8 + j][l&15]
#define MFMA16(a, b, c)                                                        \
  __builtin_amdgcn_mfma_f32_16x16x32_bf16(__builtin_bit_cast(bf16x8, (a)),     \
                                          __builtin_bit_cast(bf16x8, (b)),     \
                                          (c), 0, 0, 0)

__device__ inline short f2bfs(float f) {
  return __builtin_bit_cast(short, __float2bfloat16(f));
}

// load 8 contiguous elements as bf16 bit-pattern (converting if fp32 source)
template <typename T> __device__ inline short8 ld8bf(const T* p);
template <> __device__ inline short8 ld8bf<bf16>(const bf16* p) {
  return *(const short8*)p;
}
template <> __device__ inline short8 ld8bf<float>(const float* p) {
  f32x4 a = *(const f32x4*)p;
  f32x4 b = *(const f32x4*)(p + 4);
  short8 r;
  r[0] = f2bfs(a[0]); r[1] = f2bfs(a[1]); r[2] = f2bfs(a[2]); r[3] = f2bfs(a[3]);
  r[4] = f2bfs(b[0]); r[5] = f2bfs(b[1]); r[6] = f2bfs(b[2]); r[7] = f2bfs(b[3]);
  return r;
}

template <typename OT> __device__ inline void st1(OT* p, float v);
template <> __device__ inline void st1<bf16>(bf16* p, float v) {
  *p = __float2bfloat16(v);
}
template <> __device__ inline void st1<float>(float* p, float v) { *p = v; }

// ---------------------------------------------------------------------------
// C[M,N] = A[M,K] * B[N,K]^T + bias[N].
// A: fp32 or bf16 (template); B,bias: fp32; C: fp32 or bf16 (template).
// bf16 MFMA compute, fp32 accum. 128x128 tile, BK=64, 256 thr (2x2 waves).
// ---------------------------------------------------------------------------
template <typename AT, typename OT>
__global__ __launch_bounds__(256, 2) void gemm_bt_bias(
    const AT* __restrict__ A, const float* __restrict__ B,
    const float* __restrict__ bias, OT* __restrict__ C, int M, int N, int K) {
  __shared__ bf16 As[128][64];  // 16 KB
  __shared__ bf16 Bs[128][64];  // 16 KB

  const int tid = threadIdx.x;
  const int w = tid >> 6, l = tid & 63;
  const int wr = w >> 1, wc = w & 1;
  const int m0 = blockIdx.y * 128, n0 = blockIdx.x * 128;

  f32x4 acc[4][4] = {};

  const int srow = tid >> 3;       // 0..31
  const int scol = (tid & 7) * 8;  // 0..56

  for (int kt = 0; kt < K; kt += 64) {
    short8 aReg[4], bReg[4];
#pragma unroll
    for (int p = 0; p < 4; ++p) {
      int row = p * 32 + srow;
      aReg[p] = ld8bf(A + (size_t)(m0 + row) * K + kt + scol);
      bReg[p] = ld8bf(B + (size_t)(n0 + row) * K + kt + scol);
    }
    __syncthreads();  // previous tile's readers done (WAR)
#pragma unroll
    for (int p = 0; p < 4; ++p) {
      int row = p * 32 + srow;
      *(short8*)&As[row][scol] = aReg[p];
      *(short8*)&Bs[row][scol] = bReg[p];
    }
    __syncthreads();  // writes visible to all waves

#pragma unroll
    for (int kk = 0; kk < 2; ++kk) {
      short8 af[4], bfv[4];
#pragma unroll
      for (int i = 0; i < 4; ++i) {
        af[i]  = *(const short8*)&As[wr * 64 + i * 16 + (l & 15)]
                                   [kk * 32 + (l >> 4) * 8];
        bfv[i] = *(const short8*)&Bs[wc * 64 + i * 16 + (l & 15)]
                                   [kk * 32 + (l >> 4) * 8];
      }
#pragma unroll
      for (int i = 0; i < 4; ++i)
#pragma unroll
        for (int jn = 0; jn < 4; ++jn)
          acc[i][jn] = MFMA16(af[i], bfv[jn], acc[i][jn]);
    }
  }

#pragma unroll
  for (int i = 0; i < 4; ++i) {
    int rbase = m0 + wr * 64 + i * 16 + (l >> 4) * 4;
#pragma unroll
    for (int jn = 0; jn < 4; ++jn) {
      int col = n0 + wc * 64 + jn * 16 + (l & 15);
      float bv = bias[col];
#pragma unroll
      for (int r = 0; r < 4; ++r)
        st1(&C[(size_t)(rbase + r) * N + col], acc[i][jn][r] + bv);
    }
  }
}

// ---------------------------------------------------------------------------
// Flash attention over bf16 qkv buffer [4096][3072] (n = t*1024 + h*64 + e).
// Block = 4 waves; wave w owns 16 Q rows; Q-tile 64 rows; KV blocks of 64.
// Softmax in exp2 domain: t = s * (hd^-0.5 * log2 e).
// ---------------------------------------------------------------------------
__global__ __launch_bounds__(256, 2) void attn_fwd(
    const bf16* __restrict__ qkv, bf16* __restrict__ attended) {
  const int S = 2048, D3 = 3072, D = 1024;
  const int qt = blockIdx.x, bh = blockIdx.y;
  const int b = bh >> 4, h = bh & 15;
  const int tid = threadIdx.x, w = tid >> 6, l = tid & 63;

  __shared__ bf16 Klds[64][72];      // padded rows
  __shared__ bf16 Vt[64][72];        // V transposed: Vt[e][kv]
  __shared__ bf16 Plds[4][16][72];   // per-wave P tile (A-frag relayout)

  const int q0 = qt * 64 + w * 16;

  short8 qf[2];
  {
    size_t rowb = (size_t)(b * S + q0 + (l & 15)) * D3 + h * 64;
    qf[0] = *(const short8*)&qkv[rowb + (l >> 4) * 8];
    qf[1] = *(const short8*)&qkv[rowb + 32 + (l >> 4) * 8];
  }

  float m_i[4], l_i[4];
  f32x4 o_acc[4] = {};
#pragma unroll
  for (int r = 0; r < 4; ++r) { m_i[r] = -1e30f; l_i[r] = 0.f; }

  const float Cs = 0.125f * 1.44269504088896340736f;  // hd^-0.5 * log2(e)

  for (int kv0 = 0; kv0 < S; kv0 += 64) {
    __syncthreads();  // previous iteration's LDS readers done
#pragma unroll
    for (int c = 0; c < 2; ++c) {
      int flat = tid + c * 256;        // 0..511
      int row = flat >> 3;             // kv row 0..63
      int colg = (flat & 7) * 8;       // 0..56
      size_t gbase = (size_t)(b * S + kv0 + row) * D3 + h * 64 + colg;
      short8 kv = *(const short8*)&qkv[gbase + 1024];
      *(short8*)&Klds[row][colg] = kv;
      short8 vv = *(const short8*)&qkv[gbase + 2048];
#pragma unroll
      for (int j = 0; j < 8; ++j)
        *(short*)&Vt[colg + j][row] = vv[j];
    }
    __syncthreads();

    // S = Q @ K^T  (16 q-rows x 64 kv-cols per wave)
    f32x4 sacc[4] = {};
#pragma unroll
    for (int kk = 0; kk < 2; ++kk)
#pragma unroll
      for (int n = 0; n < 4; ++n) {
        short8 kf = *(const short8*)&Klds[n * 16 + (l & 15)]
                                        [kk * 32 + (l >> 4) * 8];
        sacc[n] = MFMA16(qf[kk], kf, sacc[n]);
      }

    // online softmax; q_local = (l>>4)*4 + r; 16 lanes hold the 64 kv cols
    float alpha[4];
#pragma unroll
    for (int r = 0; r < 4; ++r) {
      float t0 = sacc[0][r] * Cs, t1 = sacc[1][r] * Cs;
      float t2 = sacc[2][r] * Cs, t3 = sacc[3][r] * Cs;
      float mx = fmaxf(fmaxf(t0, t1), fmaxf(t2, t3));
#pragma unroll
      for (int off = 8; off > 0; off >>= 1)
        mx = fmaxf(mx, __shfl_xor(mx, off));
      float mn = fmaxf(m_i[r], mx);
      alpha[r] = exp2f(m_i[r] - mn);
      m_i[r] = mn;
      float p0 = exp2f(t0 - mn), p1 = exp2f(t1 - mn);
      float p2 = exp2f(t2 - mn), p3 = exp2f(t3 - mn);
      float rs = p0 + p1 + p2 + p3;
#pragma unroll
      for (int off = 8; off > 0; off >>= 1) rs += __shfl_xor(rs, off);
      l_i[r] = l_i[r] * alpha[r] + rs;
      int prow = (l >> 4) * 4 + r;
      Plds[w][prow][0 + (l & 15)]  = __float2bfloat16(p0);
      Plds[w][prow][16 + (l & 15)] = __float2bfloat16(p1);
      Plds[w][prow][32 + (l & 15)] = __float2bfloat16(p2);
      Plds[w][prow][48 + (l & 15)] = __float2bfloat16(p3);
      o_acc[0][r] *= alpha[r];
      o_acc[1][r] *= alpha[r];
      o_acc[2][r] *= alpha[r];
      o_acc[3][r] *= alpha[r];
    }

    // fence: Plds scalar-written above, vector-read below
    __syncthreads();

    // O += P @ V
#pragma unroll
    for (int kk = 0; kk < 2; ++kk) {
      short8 pf = *(const short8*)&Plds[w][l & 15][kk * 32 + (l >> 4) * 8];
#pragma unroll
      for (int e = 0; e < 4; ++e) {
        short8 vf = *(const short8*)&Vt[e * 16 + (l & 15)]
                                      [kk * 32 + (l >> 4) * 8];
        o_acc[e] = MFMA16(pf, vf, o_acc[e]);
      }
    }
  }

#pragma unroll
  for (int e = 0; e < 4; ++e)
#pragma unroll
    for (int r = 0; r < 4; ++r) {
      int row = q0 + (l >> 4) * 4 + r;
      int col = h * 64 + e * 16 + (l & 15);
      attended[(size_t)(b * S + row) * D + col] =
          __float2bfloat16(o_acc[e][r] / l_i[r]);
    }
}

// ---------------------------------------------------------------------------
extern "C" void kernel_launch(void* const* d_in, const int* in_sizes, int n_in,
                              void* d_out, int out_size, void* d_ws,
                              size_t ws_size, hipStream_t stream) {
  const float* x     = (const float*)d_in[0];   // [2,2048,1024] fp32
  const float* w_qkv = (const float*)d_in[1];   // [3072,1024]   fp32
  const float* b_qkv = (const float*)d_in[2];   // [3072]        fp32
  const float* w_out = (const float*)d_in[3];   // [1024,1024]   fp32
  const float* b_out = (const float*)d_in[4];   // [1024]        fp32
  float* out = (float*)d_out;                   // [2,2048,1024] fp32

  const int BS = 4096;   // B*S
  const int D = 1024, D3 = 3072;

  bf16* qkv = (bf16*)d_ws;                 // [4096][3072] bf16 (25.2 MB)
  bf16* att = qkv + (size_t)BS * D3;       // [4096][1024] bf16 (8.4 MB)

  gemm_bt_bias<float, bf16><<<dim3(D3 / 128, BS / 128), 256, 0, stream>>>(
      x, w_qkv, b_qkv, qkv, BS, D3, D);
  attn_fwd<<<dim3(32, 32), 256, 0, stream>>>(qkv, att);
  gemm_bt_bias<bf16, float><<<dim3(D / 128, BS / 128), 256, 0, stream>>>(
      att, w_out, b_out, out, BS, D, D);
}

// Round 5
// 235.761 us; speedup vs baseline: 1.1385x; 1.1385x over previous
//
#include <hip/hip_runtime.h>
#include <hip/hip_bf16.h>

typedef __hip_bfloat16 bf16;
typedef __attribute__((ext_vector_type(8))) short short8;
typedef __attribute__((ext_vector_type(8))) __bf16 bf16x8;
typedef __attribute__((ext_vector_type(4))) float f32x4;
typedef __attribute__((ext_vector_type(4))) unsigned int u32x4;

// MFMA 16x16x32 bf16: a,b are 8 bf16 (4 VGPR), c/d 4 f32.
// C/D: col = lane&15, row = (lane>>4)*4 + reg   [m89/m91]
// A:   lane l holds A[l&15][(l>>4)*8 + j]
// B:   lane l holds B[(l>>4)*8 + j][l&15]
#define MFMA16(a, b, c)                                                        \
  __builtin_amdgcn_mfma_f32_16x16x32_bf16(__builtin_bit_cast(bf16x8, (a)),     \
                                          __builtin_bit_cast(bf16x8, (b)),     \
                                          (c), 0, 0, 0)

__device__ inline short f2bfs(float f) {
  return __builtin_bit_cast(short, __float2bfloat16(f));
}

template <typename T> __device__ inline short8 ld8bf(const T* p);
template <> __device__ inline short8 ld8bf<bf16>(const bf16* p) {
  return *(const short8*)p;
}
template <> __device__ inline short8 ld8bf<float>(const float* p) {
  f32x4 a = *(const f32x4*)p;
  f32x4 b = *(const f32x4*)(p + 4);
  short8 r;
  r[0] = f2bfs(a[0]); r[1] = f2bfs(a[1]); r[2] = f2bfs(a[2]); r[3] = f2bfs(a[3]);
  r[4] = f2bfs(b[0]); r[5] = f2bfs(b[1]); r[6] = f2bfs(b[2]); r[7] = f2bfs(b[3]);
  return r;
}

template <typename OT> __device__ inline void st1(OT* p, float v);
template <> __device__ inline void st1<bf16>(bf16* p, float v) {
  *p = __float2bfloat16(v);
}
template <> __device__ inline void st1<float>(float* p, float v) { *p = v; }

__device__ inline unsigned int funnel16(unsigned int hi, unsigned int lo) {
  return (unsigned int)(((((unsigned long long)hi) << 32) | lo) >> 16);
}

// u[j] = v[(j + r) & 7] — left-rotate 8 shorts by r, all-static indexing
// (3 stages: 1-word rot, 2-word rot, 1-short funnel; ~12 VALU).
__device__ inline short8 rotl8(short8 v, int r) {
  u32x4 W = __builtin_bit_cast(u32x4, v);
  u32x4 T, U, F;
  int wr = r >> 1;
  T[0] = (wr & 1) ? W[1] : W[0];
  T[1] = (wr & 1) ? W[2] : W[1];
  T[2] = (wr & 1) ? W[3] : W[2];
  T[3] = (wr & 1) ? W[0] : W[3];
  U[0] = (wr & 2) ? T[2] : T[0];
  U[1] = (wr & 2) ? T[3] : T[1];
  U[2] = (wr & 2) ? T[0] : T[2];
  U[3] = (wr & 2) ? T[1] : T[3];
  F[0] = (r & 1) ? funnel16(U[1], U[0]) : U[0];
  F[1] = (r & 1) ? funnel16(U[2], U[1]) : U[1];
  F[2] = (r & 1) ? funnel16(U[3], U[2]) : U[2];
  F[3] = (r & 1) ? funnel16(U[0], U[3]) : U[3];
  return __builtin_bit_cast(short8, F);
}

// ---------------------------------------------------------------------------
// C[M,N] = A[M,K] * B[N,K]^T + bias[N].  (unchanged from round 4 — passing)
// ---------------------------------------------------------------------------
template <typename AT, typename OT>
__global__ __launch_bounds__(256, 2) void gemm_bt_bias(
    const AT* __restrict__ A, const float* __restrict__ B,
    const float* __restrict__ bias, OT* __restrict__ C, int M, int N, int K) {
  __shared__ bf16 As[128][64];
  __shared__ bf16 Bs[128][64];

  const int tid = threadIdx.x;
  const int w = tid >> 6, l = tid & 63;
  const int wr = w >> 1, wc = w & 1;
  const int m0 = blockIdx.y * 128, n0 = blockIdx.x * 128;

  f32x4 acc[4][4] = {};

  const int srow = tid >> 3;
  const int scol = (tid & 7) * 8;

  for (int kt = 0; kt < K; kt += 64) {
    short8 aReg[4], bReg[4];
#pragma unroll
    for (int p = 0; p < 4; ++p) {
      int row = p * 32 + srow;
      aReg[p] = ld8bf(A + (size_t)(m0 + row) * K + kt + scol);
      bReg[p] = ld8bf(B + (size_t)(n0 + row) * K + kt + scol);
    }
    __syncthreads();
#pragma unroll
    for (int p = 0; p < 4; ++p) {
      int row = p * 32 + srow;
      *(short8*)&As[row][scol] = aReg[p];
      *(short8*)&Bs[row][scol] = bReg[p];
    }
    __syncthreads();

#pragma unroll
    for (int kk = 0; kk < 2; ++kk) {
      short8 af[4], bfv[4];
#pragma unroll
      for (int i = 0; i < 4; ++i) {
        af[i]  = *(const short8*)&As[wr * 64 + i * 16 + (l & 15)]
                                   [kk * 32 + (l >> 4) * 8];
        bfv[i] = *(const short8*)&Bs[wc * 64 + i * 16 + (l & 15)]
                                   [kk * 32 + (l >> 4) * 8];
      }
#pragma unroll
      for (int i = 0; i < 4; ++i)
#pragma unroll
        for (int jn = 0; jn < 4; ++jn)
          acc[i][jn] = MFMA16(af[i], bfv[jn], acc[i][jn]);
    }
  }

#pragma unroll
  for (int i = 0; i < 4; ++i) {
    int rbase = m0 + wr * 64 + i * 16 + (l >> 4) * 4;
#pragma unroll
    for (int jn = 0; jn < 4; ++jn) {
      int col = n0 + wc * 64 + jn * 16 + (l & 15);
      float bv = bias[col];
#pragma unroll
      for (int r = 0; r < 4; ++r)
        st1(&C[(size_t)(rbase + r) * N + col], acc[i][jn][r] + bv);
    }
  }
}

// ---------------------------------------------------------------------------
// Flash attention, bf16 qkv [4096][3072] (n = plane*1024 + h*64 + e).
// 512 thr = 8 waves; wave w owns 16 q rows; Q-tile 128/block; KV blocks 64.
// Bank-conflict-free LDS writes via per-lane column rotation.
// ---------------------------------------------------------------------------
__global__ __launch_bounds__(512, 4) void attn_fwd(
    const bf16* __restrict__ qkv, bf16* __restrict__ attended) {
  const int S = 2048, D3 = 3072, D = 1024;
  const int qt = blockIdx.x, bh = blockIdx.y;
  const int b = bh >> 4, h = bh & 15;
  const int tid = threadIdx.x, w = tid >> 6, l = tid & 63;

  __shared__ bf16 Klds[64][72];      // 9.2 KB
  __shared__ bf16 Vt[64][72];        // 9.2 KB, Vt[e][kv]
  __shared__ bf16 Plds[8][16][72];   // 18.4 KB, per-wave P tile

  const int q0 = qt * 128 + w * 16;

  short8 qf[2];
  {
    size_t rowb = (size_t)(b * S + q0 + (l & 15)) * D3 + h * 64;
    qf[0] = *(const short8*)&qkv[rowb + (l >> 4) * 8];
    qf[1] = *(const short8*)&qkv[rowb + 32 + (l >> 4) * 8];
  }

  float m_i[4], l_i[4];
  f32x4 o_acc[4] = {};
#pragma unroll
  for (int r = 0; r < 4; ++r) { m_i[r] = -1e30f; l_i[r] = 0.f; }

  const float Cs = 0.125f * 1.44269504088896340736f;  // hd^-0.5 * log2(e)

  // one staging slot per thread: 512 slots = 64 rows x 8 col-chunks
  const int srow = tid >> 3;
  const int sI = tid & 7;            // col-chunk index (rotation seed)
  const int scolg = sI * 8;

  for (int kv0 = 0; kv0 < S; kv0 += 64) {
    __syncthreads();  // WAR: previous tile's readers done
    {
      size_t gbase = (size_t)(b * S + kv0 + srow) * D3 + h * 64 + scolg;
      short8 kvv = *(const short8*)&qkv[gbase + 1024];
      *(short8*)&Klds[srow][scolg] = kvv;
      short8 vv = *(const short8*)&qkv[gbase + 2048];
      short8 u = rotl8(vv, sI);      // u[j] = vv[(j+sI)&7]
#pragma unroll
      for (int j = 0; j < 8; ++j) {
        int jj = (j + sI) & 7;       // step j: lanes hit 32 distinct banks
        *(short*)&Vt[scolg + jj][srow] = (short)u[j];
      }
    }
    __syncthreads();

    // S = Q @ K^T  (16 q-rows x 64 kv-cols per wave)
    f32x4 sacc[4] = {};
#pragma unroll
    for (int kk = 0; kk < 2; ++kk)
#pragma unroll
      for (int n = 0; n < 4; ++n) {
        short8 kf = *(const short8*)&Klds[n * 16 + (l & 15)]
                                        [kk * 32 + (l >> 4) * 8];
        sacc[n] = MFMA16(qf[kk], kf, sacc[n]);
      }

    // online softmax; q_local = (l>>4)*4 + r; 16 lanes hold the 64 kv cols
    const int G = l >> 4;
#pragma unroll
    for (int r = 0; r < 4; ++r) {
      float t0 = sacc[0][r] * Cs, t1 = sacc[1][r] * Cs;
      float t2 = sacc[2][r] * Cs, t3 = sacc[3][r] * Cs;
      float mx = fmaxf(fmaxf(t0, t1), fmaxf(t2, t3));
#pragma unroll
      for (int off = 8; off > 0; off >>= 1)
        mx = fmaxf(mx, __shfl_xor(mx, off));
      float mn = fmaxf(m_i[r], mx);
      float alpha = exp2f(m_i[r] - mn);
      m_i[r] = mn;
      float p0 = exp2f(t0 - mn), p1 = exp2f(t1 - mn);
      float p2 = exp2f(t2 - mn), p3 = exp2f(t3 - mn);
      float rs = p0 + p1 + p2 + p3;
#pragma unroll
      for (int off = 8; off > 0; off >>= 1) rs += __shfl_xor(rs, off);
      l_i[r] = l_i[r] * alpha + rs;
      int prow = G * 4 + r;
      // rotate (p0..p3) left by G (static-index cndmask stages), store at
      // column block (c+G)&3: step c hits 4 disjoint bank octets -> no conflict
      float a0 = (G & 1) ? p1 : p0, a1 = (G & 1) ? p2 : p1;
      float a2 = (G & 1) ? p3 : p2, a3 = (G & 1) ? p0 : p3;
      float q0v = (G & 2) ? a2 : a0, q1v = (G & 2) ? a3 : a1;
      float q2v = (G & 2) ? a0 : a2, q3v = (G & 2) ? a1 : a3;
      int c0 = G & 3, c1 = (G + 1) & 3, c2 = (G + 2) & 3, c3 = (G + 3) & 3;
      Plds[w][prow][c0 * 16 + (l & 15)] = __float2bfloat16(q0v);
      Plds[w][prow][c1 * 16 + (l & 15)] = __float2bfloat16(q1v);
      Plds[w][prow][c2 * 16 + (l & 15)] = __float2bfloat16(q2v);
      Plds[w][prow][c3 * 16 + (l & 15)] = __float2bfloat16(q3v);
      o_acc[0][r] *= alpha;
      o_acc[1][r] *= alpha;
      o_acc[2][r] *= alpha;
      o_acc[3][r] *= alpha;
    }

    // fence: Plds scalar-written above, vector-read below (TBAA + HW sync)
    __syncthreads();

    // O += P @ V
#pragma unroll
    for (int kk = 0; kk < 2; ++kk) {
      short8 pf = *(const short8*)&Plds[w][l & 15][kk * 32 + (l >> 4) * 8];
#pragma unroll
      for (int e = 0; e < 4; ++e) {
        short8 vf = *(const short8*)&Vt[e * 16 + (l & 15)]
                                      [kk * 32 + (l >> 4) * 8];
        o_acc[e] = MFMA16(pf, vf, o_acc[e]);
      }
    }
  }

#pragma unroll
  for (int e = 0; e < 4; ++e)
#pragma unroll
    for (int r = 0; r < 4; ++r) {
      int row = q0 + (l >> 4) * 4 + r;
      int col = h * 64 + e * 16 + (l & 15);
      attended[(size_t)(b * S + row) * D + col] =
          __float2bfloat16(o_acc[e][r] / l_i[r]);
    }
}

// ---------------------------------------------------------------------------
extern "C" void kernel_launch(void* const* d_in, const int* in_sizes, int n_in,
                              void* d_out, int out_size, void* d_ws,
                              size_t ws_size, hipStream_t stream) {
  const float* x     = (const float*)d_in[0];   // [2,2048,1024] fp32
  const float* w_qkv = (const float*)d_in[1];   // [3072,1024]   fp32
  const float* b_qkv = (const float*)d_in[2];   // [3072]        fp32
  const float* w_out = (const float*)d_in[3];   // [1024,1024]   fp32
  const float* b_out = (const float*)d_in[4];   // [1024]        fp32
  float* out = (float*)d_out;                   // [2,2048,1024] fp32

  const int BS = 4096;   // B*S
  const int D = 1024, D3 = 3072;

  bf16* qkv = (bf16*)d_ws;                 // [4096][3072] bf16
  bf16* att = qkv + (size_t)BS * D3;       // [4096][1024] bf16

  gemm_bt_bias<float, bf16><<<dim3(D3 / 128, BS / 128), 256, 0, stream>>>(
      x, w_qkv, b_qkv, qkv, BS, D3, D);
  attn_fwd<<<dim3(16, 32), 512, 0, stream>>>(qkv, att);
  gemm_bt_bias<bf16, float><<<dim3(D / 128, BS / 128), 256, 0, stream>>>(
      att, w_out, b_out, out, BS, D, D);
}

// Round 6
// 157.602 us; speedup vs baseline: 1.7032x; 1.4959x over previous
//
#include <hip/hip_runtime.h>
#include <hip/hip_bf16.h>

typedef __hip_bfloat16 bf16;
typedef __attribute__((ext_vector_type(8))) short short8;
typedef __attribute__((ext_vector_type(8))) __bf16 bf16x8;
typedef __attribute__((ext_vector_type(4))) float f32x4;
typedef __attribute__((ext_vector_type(16))) float f32x16;
typedef __attribute__((ext_vector_type(4))) unsigned int u32x4;
typedef __attribute__((ext_vector_type(2))) unsigned int u32x2;

// 16x16x32: C/D col = lane&15, row = (lane>>4)*4 + reg  [m89/m91]
//           A: lane holds A[l&15][(l>>4)*8+j]; B: B[(l>>4)*8+j][l&15]
#define MFMA16(a, b, c)                                                        \
  __builtin_amdgcn_mfma_f32_16x16x32_bf16(__builtin_bit_cast(bf16x8, (a)),     \
                                          __builtin_bit_cast(bf16x8, (b)),     \
                                          (c), 0, 0, 0)
// 32x32x16: C/D col = lane&31, row = (reg&3)+8*(reg>>2)+4*(lane>>5) [m74/m101]
//           A: lane holds A[l&31][(l>>5)*8+j]; B: B[(l>>5)*8+j][l&31]
#define MFMA32(a, b, c)                                                        \
  __builtin_amdgcn_mfma_f32_32x32x16_bf16(__builtin_bit_cast(bf16x8, (a)),     \
                                          __builtin_bit_cast(bf16x8, (b)),     \
                                          (c), 0, 0, 0)

__device__ inline short f2bfs(float f) {
  return __builtin_bit_cast(short, __float2bfloat16(f));
}
__device__ inline unsigned pk2(float lo, float hi) {
  unsigned a = (unsigned short)__builtin_bit_cast(short, __float2bfloat16(lo));
  unsigned b = (unsigned short)__builtin_bit_cast(short, __float2bfloat16(hi));
  return a | (b << 16);
}

template <typename T> __device__ inline short8 ld8bf(const T* p);
template <> __device__ inline short8 ld8bf<bf16>(const bf16* p) {
  return *(const short8*)p;
}
template <> __device__ inline short8 ld8bf<float>(const float* p) {
  f32x4 a = *(const f32x4*)p;
  f32x4 b = *(const f32x4*)(p + 4);
  short8 r;
  r[0] = f2bfs(a[0]); r[1] = f2bfs(a[1]); r[2] = f2bfs(a[2]); r[3] = f2bfs(a[3]);
  r[4] = f2bfs(b[0]); r[5] = f2bfs(b[1]); r[6] = f2bfs(b[2]); r[7] = f2bfs(b[3]);
  return r;
}

template <typename OT> __device__ inline void st1(OT* p, float v);
template <> __device__ inline void st1<bf16>(bf16* p, float v) {
  *p = __float2bfloat16(v);
}
template <> __device__ inline void st1<float>(float* p, float v) { *p = v; }

__device__ inline unsigned int funnel16(unsigned int hi, unsigned int lo) {
  return (unsigned int)(((((unsigned long long)hi) << 32) | lo) >> 16);
}
// u[j] = v[(j + r) & 7] — rotate 8 shorts left by r, all-static indexing.
__device__ inline short8 rotl8(short8 v, int r) {
  u32x4 W = __builtin_bit_cast(u32x4, v);
  u32x4 T, U, F;
  int wr = r >> 1;
  T[0] = (wr & 1) ? W[1] : W[0];
  T[1] = (wr & 1) ? W[2] : W[1];
  T[2] = (wr & 1) ? W[3] : W[2];
  T[3] = (wr & 1) ? W[0] : W[3];
  U[0] = (wr & 2) ? T[2] : T[0];
  U[1] = (wr & 2) ? T[3] : T[1];
  U[2] = (wr & 2) ? T[0] : T[2];
  U[3] = (wr & 2) ? T[1] : T[3];
  F[0] = (r & 1) ? funnel16(U[1], U[0]) : U[0];
  F[1] = (r & 1) ? funnel16(U[2], U[1]) : U[1];
  F[2] = (r & 1) ? funnel16(U[3], U[2]) : U[2];
  F[3] = (r & 1) ? funnel16(U[0], U[3]) : U[3];
  return __builtin_bit_cast(short8, F);
}

// ---------------------------------------------------------------------------
// C[M,N] = A[M,K] * B[N,K]^T + bias[N]. (unchanged — passing since R4)
// ---------------------------------------------------------------------------
template <typename AT, typename OT>
__global__ __launch_bounds__(256, 2) void gemm_bt_bias(
    const AT* __restrict__ A, const float* __restrict__ B,
    const float* __restrict__ bias, OT* __restrict__ C, int M, int N, int K) {
  __shared__ bf16 As[128][64];
  __shared__ bf16 Bs[128][64];

  const int tid = threadIdx.x;
  const int w = tid >> 6, l = tid & 63;
  const int wr = w >> 1, wc = w & 1;
  const int m0 = blockIdx.y * 128, n0 = blockIdx.x * 128;

  f32x4 acc[4][4] = {};

  const int srow = tid >> 3;
  const int scol = (tid & 7) * 8;

  for (int kt = 0; kt < K; kt += 64) {
    short8 aReg[4], bReg[4];
#pragma unroll
    for (int p = 0; p < 4; ++p) {
      int row = p * 32 + srow;
      aReg[p] = ld8bf(A + (size_t)(m0 + row) * K + kt + scol);
      bReg[p] = ld8bf(B + (size_t)(n0 + row) * K + kt + scol);
    }
    __syncthreads();
#pragma unroll
    for (int p = 0; p < 4; ++p) {
      int row = p * 32 + srow;
      *(short8*)&As[row][scol] = aReg[p];
      *(short8*)&Bs[row][scol] = bReg[p];
    }
    __syncthreads();

#pragma unroll
    for (int kk = 0; kk < 2; ++kk) {
      short8 af[4], bfv[4];
#pragma unroll
      for (int i = 0; i < 4; ++i) {
        af[i]  = *(const short8*)&As[wr * 64 + i * 16 + (l & 15)]
                                   [kk * 32 + (l >> 4) * 8];
        bfv[i] = *(const short8*)&Bs[wc * 64 + i * 16 + (l & 15)]
                                   [kk * 32 + (l >> 4) * 8];
      }
#pragma unroll
      for (int i = 0; i < 4; ++i)
#pragma unroll
        for (int jn = 0; jn < 4; ++jn)
          acc[i][jn] = MFMA16(af[i], bfv[jn], acc[i][jn]);
    }
  }

#pragma unroll
  for (int i = 0; i < 4; ++i) {
    int rbase = m0 + wr * 64 + i * 16 + (l >> 4) * 4;
#pragma unroll
    for (int jn = 0; jn < 4; ++jn) {
      int col = n0 + wc * 64 + jn * 16 + (l & 15);
      float bv = bias[col];
#pragma unroll
      for (int r = 0; r < 4; ++r)
        st1(&C[(size_t)(rbase + r) * N + col], acc[i][jn][r] + bv);
    }
  }
}

// ---------------------------------------------------------------------------
// Flash attention, swapped-operand 32x32 MFMA form.
// 256 thr = 4 waves; wave owns 32 q rows (QBLK=128); KV blocks of 64.
// S^T = mfma(K, Q): lane l owns q-col (l&31); kv rows (r&3)+8*(r>>2)+4*hi+32n.
// Softmax per-lane scalar; P exchanged lane<->lane^32 via one shfl per pair.
// O^T = mfma(V^T, P^T): same col=q layout -> per-lane alpha rescale.
// ---------------------------------------------------------------------------
__global__ __launch_bounds__(256, 2) void attn_fwd(
    const bf16* __restrict__ qkv, bf16* __restrict__ attended) {
  const int S = 2048, D3 = 3072, D = 1024;
  const int qt = blockIdx.x, bh = blockIdx.y;
  const int b = bh >> 4, h = bh & 15;
  const int tid = threadIdx.x, w = tid >> 6, l = tid & 63;
  const int lo5 = l & 31, hi = l >> 5;

  __shared__ bf16 Klds[64][72];  // 9.2 KB, K[kv][e]
  __shared__ bf16 Vt[64][72];    // 9.2 KB, V^T[e][kv]

  const int q0w = qt * 128 + w * 32;

  // Q B-fragments (hoisted): qf[ks] = Q[q0w+lo5][ks*16 + hi*8 .. +7]
  short8 qf[4];
  {
    size_t qrow = (size_t)(b * S + q0w + lo5) * D3 + h * 64;
#pragma unroll
    for (int ks = 0; ks < 4; ++ks)
      qf[ks] = *(const short8*)&qkv[qrow + ks * 16 + hi * 8];
  }

  float m_raw = -1e30f, l_i = 0.f;
  f32x16 o0 = {}, o1 = {};

  const float Cs = 0.125f * 1.44269504088896340736f;  // hd^-0.5 * log2(e)

  // staging map: thread t -> kv row t>>2, col chunk (t&3)*16 (+0 / +8)
  const int srow = tid >> 2;
  const int scq = tid & 3;

  // prologue loads (tile 0)
  short8 k0, k1, v0, v1;
  {
    size_t gb = (size_t)(b * S + srow) * D3 + h * 64 + scq * 16;
    k0 = *(const short8*)&qkv[gb + 1024];
    k1 = *(const short8*)&qkv[gb + 1024 + 8];
    v0 = *(const short8*)&qkv[gb + 2048];
    v1 = *(const short8*)&qkv[gb + 2048 + 8];
  }

  for (int kv0 = 0; kv0 < S; kv0 += 64) {
    __syncthreads();  // WAR: previous tile's readers done
    // write staged K tile
    *(short8*)&Klds[srow][scq * 16] = k0;
    *(short8*)&Klds[srow][scq * 16 + 8] = k1;
    // write staged V transposed (rotation -> conflict-free column scatter)
#pragma unroll
    for (int g = 0; g < 2; ++g) {
      int sI = scq * 2 + g;
      short8 u = rotl8(g ? v1 : v0, sI);
#pragma unroll
      for (int j = 0; j < 8; ++j) {
        int jj = (j + sI) & 7;
        *(short*)&Vt[sI * 8 + jj][srow] = (short)u[j];
      }
    }
    __syncthreads();  // writes visible

    // prefetch next tile during compute (T14-lite)
    if (kv0 + 64 < S) {
      size_t gb = (size_t)(b * S + kv0 + 64 + srow) * D3 + h * 64 + scq * 16;
      k0 = *(const short8*)&qkv[gb + 1024];
      k1 = *(const short8*)&qkv[gb + 1024 + 8];
      v0 = *(const short8*)&qkv[gb + 2048];
      v1 = *(const short8*)&qkv[gb + 2048 + 8];
    }

    // S^T = K @ Q^T : s_n holds S[q=lo5][kv = 32n + (r&3)+8*(r>>2)+4*hi]
    f32x16 s0 = {}, s1 = {};
#pragma unroll
    for (int ks = 0; ks < 4; ++ks) {
      short8 ka0 = *(const short8*)&Klds[lo5][ks * 16 + hi * 8];
      short8 ka1 = *(const short8*)&Klds[32 + lo5][ks * 16 + hi * 8];
      s0 = MFMA32(ka0, qf[ks], s0);
      s1 = MFMA32(ka1, qf[ks], s1);
    }

    // per-lane online softmax (q = lo5; partner lane l^32 has other 32 kv)
    f32x16 tm;
#pragma unroll
    for (int r = 0; r < 16; ++r) tm[r] = fmaxf(s0[r], s1[r]);
#pragma unroll
    for (int st = 8; st > 0; st >>= 1)
#pragma unroll
      for (int r = 0; r < st; ++r) tm[r] = fmaxf(tm[r], tm[r + st]);
    float mx = fmaxf(tm[0], __shfl_xor(tm[0], 32));
    float mn = fmaxf(m_raw, mx);
    float alpha = __builtin_amdgcn_exp2f((m_raw - mn) * Cs);
    m_raw = mn;
    float pc = mn * Cs;

    f32x16 e0, e1;
#pragma unroll
    for (int r = 0; r < 16; ++r) {
      e0[r] = __builtin_amdgcn_exp2f(__builtin_fmaf(s0[r], Cs, -pc));
      e1[r] = __builtin_amdgcn_exp2f(__builtin_fmaf(s1[r], Cs, -pc));
    }
    f32x16 ts;
#pragma unroll
    for (int r = 0; r < 16; ++r) ts[r] = e0[r] + e1[r];
#pragma unroll
    for (int st = 8; st > 0; st >>= 1)
#pragma unroll
      for (int r = 0; r < st; ++r) ts[r] += ts[r + st];
    float sf = ts[0] + __shfl_xor(ts[0], 32);
    l_i = l_i * alpha + sf;
    o0 *= alpha;
    o1 *= alpha;

    // pack P quads: po[g][t] covers kv = 32g + 8t + 4hi + {0..3}
    unsigned po[2][4][2];
#pragma unroll
    for (int t = 0; t < 4; ++t) {
      po[0][t][0] = pk2(e0[4 * t], e0[4 * t + 1]);
      po[0][t][1] = pk2(e0[4 * t + 2], e0[4 * t + 3]);
      po[1][t][0] = pk2(e1[4 * t], e1[4 * t + 1]);
      po[1][t][1] = pk2(e1[4 * t + 2], e1[4 * t + 3]);
    }
    // exchange with partner lane: hi sends even-quads, lo sends odd-quads,
    // each receives exactly the quad it needs (pre-selected, 1 shfl each)
    unsigned pr[2][2][2];
#pragma unroll
    for (int g = 0; g < 2; ++g)
#pragma unroll
      for (int p = 0; p < 2; ++p)
#pragma unroll
        for (int hf = 0; hf < 2; ++hf) {
          unsigned y = hi ? po[g][2 * p][hf] : po[g][2 * p + 1][hf];
          pr[g][p][hf] = (unsigned)__shfl_xor((int)y, 32);
        }

    // O^T += V^T @ P^T
#pragma unroll
    for (int ks = 0; ks < 4; ++ks) {
      const int g = ks >> 1, p = ks & 1;
      u32x4 fw;
      fw[0] = hi ? pr[g][p][0] : po[g][2 * p][0];
      fw[1] = hi ? pr[g][p][1] : po[g][2 * p][1];
      fw[2] = hi ? po[g][2 * p + 1][0] : pr[g][p][0];
      fw[3] = hi ? po[g][2 * p + 1][1] : pr[g][p][1];
      short8 pf = __builtin_bit_cast(short8, fw);
      short8 va0 = *(const short8*)&Vt[lo5][ks * 16 + hi * 8];
      short8 va1 = *(const short8*)&Vt[32 + lo5][ks * 16 + hi * 8];
      o0 = MFMA32(va0, pf, o0);
      o1 = MFMA32(va1, pf, o1);
    }
  }

  // epilogue: O[q][e] = o{eg}[r]/l_i at e = 32eg + 8*(r>>2) + 4hi + (r&3)
  float inv = 1.0f / l_i;
  size_t orow = (size_t)(b * S + q0w + lo5) * D + h * 64;
#pragma unroll
  for (int t = 0; t < 4; ++t) {
    u32x2 w0, w1;
    w0[0] = pk2(o0[4 * t] * inv, o0[4 * t + 1] * inv);
    w0[1] = pk2(o0[4 * t + 2] * inv, o0[4 * t + 3] * inv);
    w1[0] = pk2(o1[4 * t] * inv, o1[4 * t + 1] * inv);
    w1[1] = pk2(o1[4 * t + 2] * inv, o1[4 * t + 3] * inv);
    *(u32x2*)&attended[orow + 8 * t + 4 * hi] = w0;
    *(u32x2*)&attended[orow + 32 + 8 * t + 4 * hi] = w1;
  }
}

// ---------------------------------------------------------------------------
extern "C" void kernel_launch(void* const* d_in, const int* in_sizes, int n_in,
                              void* d_out, int out_size, void* d_ws,
                              size_t ws_size, hipStream_t stream) {
  const float* x     = (const float*)d_in[0];   // [2,2048,1024] fp32
  const float* w_qkv = (const float*)d_in[1];   // [3072,1024]   fp32
  const float* b_qkv = (const float*)d_in[2];   // [3072]        fp32
  const float* w_out = (const float*)d_in[3];   // [1024,1024]   fp32
  const float* b_out = (const float*)d_in[4];   // [1024]        fp32
  float* out = (float*)d_out;                   // [2,2048,1024] fp32

  const int BS = 4096;   // B*S
  const int D = 1024, D3 = 3072;

  bf16* qkv = (bf16*)d_ws;                 // [4096][3072] bf16
  bf16* att = qkv + (size_t)BS * D3;       // [4096][1024] bf16

  gemm_bt_bias<float, bf16><<<dim3(D3 / 128, BS / 128), 256, 0, stream>>>(
      x, w_qkv, b_qkv, qkv, BS, D3, D);
  attn_fwd<<<dim3(16, 32), 256, 0, stream>>>(qkv, att);
  gemm_bt_bias<bf16, float><<<dim3(D / 128, BS / 128), 256, 0, stream>>>(
      att, w_out, b_out, out, BS, D, D);
}

// Round 7
// 130.509 us; speedup vs baseline: 2.0567x; 1.2076x over previous
//
#include <hip/hip_runtime.h>
#include <hip/hip_bf16.h>

typedef __hip_bfloat16 bf16;
typedef __attribute__((ext_vector_type(8))) short short8;
typedef __attribute__((ext_vector_type(8))) __bf16 bf16x8;
typedef __attribute__((ext_vector_type(4))) float f32x4;
typedef __attribute__((ext_vector_type(16))) float f32x16;
typedef __attribute__((ext_vector_type(4))) unsigned int u32x4;
typedef __attribute__((ext_vector_type(2))) unsigned int u32x2;

// 16x16x32: C/D col = lane&15, row = (lane>>4)*4 + reg  [m89/m91]
#define MFMA16(a, b, c)                                                        \
  __builtin_amdgcn_mfma_f32_16x16x32_bf16(__builtin_bit_cast(bf16x8, (a)),     \
                                          __builtin_bit_cast(bf16x8, (b)),     \
                                          (c), 0, 0, 0)
// 32x32x16: C/D col = lane&31, row = (reg&3)+8*(reg>>2)+4*(lane>>5) [m74/m101]
#define MFMA32(a, b, c)                                                        \
  __builtin_amdgcn_mfma_f32_32x32x16_bf16(__builtin_bit_cast(bf16x8, (a)),     \
                                          __builtin_bit_cast(bf16x8, (b)),     \
                                          (c), 0, 0, 0)

// async global->LDS, 16B/lane; LDS dest = wave-uniform base + lane*16 [m97]
#define GLD16(gsrc, ldst)                                                      \
  __builtin_amdgcn_global_load_lds(                                            \
      (const __attribute__((address_space(1))) void*)(gsrc),                   \
      (__attribute__((address_space(3))) void*)(ldst), 16, 0, 0)

__device__ inline short f2bfs(float f) {
  return __builtin_bit_cast(short, __float2bfloat16(f));
}
__device__ inline unsigned pk2(float lo, float hi) {
  unsigned a = (unsigned short)__builtin_bit_cast(short, __float2bfloat16(lo));
  unsigned b = (unsigned short)__builtin_bit_cast(short, __float2bfloat16(hi));
  return a | (b << 16);
}

template <typename T> __device__ inline short8 ld8bf(const T* p);
template <> __device__ inline short8 ld8bf<bf16>(const bf16* p) {
  return *(const short8*)p;
}
template <> __device__ inline short8 ld8bf<float>(const float* p) {
  f32x4 a = *(const f32x4*)p;
  f32x4 b = *(const f32x4*)(p + 4);
  short8 r;
  r[0] = f2bfs(a[0]); r[1] = f2bfs(a[1]); r[2] = f2bfs(a[2]); r[3] = f2bfs(a[3]);
  r[4] = f2bfs(b[0]); r[5] = f2bfs(b[1]); r[6] = f2bfs(b[2]); r[7] = f2bfs(b[3]);
  return r;
}

template <typename OT> __device__ inline void st1(OT* p, float v);
template <> __device__ inline void st1<bf16>(bf16* p, float v) {
  *p = __float2bfloat16(v);
}
template <> __device__ inline void st1<float>(float* p, float v) { *p = v; }

__device__ inline unsigned int funnel16(unsigned int hi, unsigned int lo) {
  return (unsigned int)(((((unsigned long long)hi) << 32) | lo) >> 16);
}
// u[j] = v[(j + r) & 7] — rotate 8 shorts left by r, all-static indexing.
__device__ inline short8 rotl8(short8 v, int r) {
  u32x4 W = __builtin_bit_cast(u32x4, v);
  u32x4 T, U, F;
  int wr = r >> 1;
  T[0] = (wr & 1) ? W[1] : W[0];
  T[1] = (wr & 1) ? W[2] : W[1];
  T[2] = (wr & 1) ? W[3] : W[2];
  T[3] = (wr & 1) ? W[0] : W[3];
  U[0] = (wr & 2) ? T[2] : T[0];
  U[1] = (wr & 2) ? T[3] : T[1];
  U[2] = (wr & 2) ? T[0] : T[2];
  U[3] = (wr & 2) ? T[1] : T[3];
  F[0] = (r & 1) ? funnel16(U[1], U[0]) : U[0];
  F[1] = (r & 1) ? funnel16(U[2], U[1]) : U[1];
  F[2] = (r & 1) ? funnel16(U[3], U[2]) : U[2];
  F[3] = (r & 1) ? funnel16(U[0], U[3]) : U[3];
  return __builtin_bit_cast(short8, F);
}

// ---------------------------------------------------------------------------
// cvt3: fp32 -> bf16 for three arrays (x, w_qkv, w_out), 8 elems/thread.
// ---------------------------------------------------------------------------
__global__ __launch_bounds__(256) void cvt3(
    const float* __restrict__ s0, bf16* __restrict__ d0, int n0,
    const float* __restrict__ s1, bf16* __restrict__ d1, int n1,
    const float* __restrict__ s2, bf16* __restrict__ d2, int n2) {
  int i = (blockIdx.x * 256 + threadIdx.x) * 8;
  if (i < n0) {
    *(short8*)&d0[i] = ld8bf(s0 + i);
  } else if ((i -= n0) < n1) {
    *(short8*)&d1[i] = ld8bf(s1 + i);
  } else if ((i -= n1) < n2) {
    *(short8*)&d2[i] = ld8bf(s2 + i);
  }
}

// ---------------------------------------------------------------------------
// FAST GEMM (m97 structure): all-bf16 operands, global_load_lds width-16,
// 128x128 tile, BK=64, 256 thr (2x2 waves, 64x64/wave), fp32 accum.
// C[M,N] = A[M,K] * B[N,K]^T + bias[N]
// ---------------------------------------------------------------------------
template <typename OT>
__global__ __launch_bounds__(256, 2) void gemm_lds_bias(
    const bf16* __restrict__ A, const bf16* __restrict__ B,
    const float* __restrict__ bias, OT* __restrict__ C, int M, int N, int K) {
  __shared__ bf16 As[128][64];  // 16 KB, linear (required by global_load_lds)
  __shared__ bf16 Bs[128][64];  // 16 KB

  const int tid = threadIdx.x;
  const int w = tid >> 6, l = tid & 63;
  const int wr = w >> 1, wc = w & 1;
  const int m0 = blockIdx.y * 128, n0 = blockIdx.x * 128;

  f32x4 acc[4][4] = {};

  const int srow = l >> 3;        // row within 8-row chunk
  const int scol = (l & 7) * 8;   // col, 16B granules

  for (int kt = 0; kt < K; kt += 64) {
#pragma unroll
    for (int j = 0; j < 4; ++j) {
      int chunk = w * 4 + j;            // 0..15, wave-uniform
      int row = chunk * 8 + srow;       // 0..127, per-lane
      GLD16(A + (size_t)(m0 + row) * K + kt + scol, &As[0][0] + chunk * 512);
      GLD16(B + (size_t)(n0 + row) * K + kt + scol, &Bs[0][0] + chunk * 512);
    }
    __syncthreads();  // drains vmcnt(0) then barrier

#pragma unroll
    for (int kk = 0; kk < 2; ++kk) {
      short8 af[4], bfv[4];
#pragma unroll
      for (int i = 0; i < 4; ++i) {
        af[i]  = *(const short8*)&As[wr * 64 + i * 16 + (l & 15)]
                                   [kk * 32 + (l >> 4) * 8];
        bfv[i] = *(const short8*)&Bs[wc * 64 + i * 16 + (l & 15)]
                                   [kk * 32 + (l >> 4) * 8];
      }
#pragma unroll
      for (int i = 0; i < 4; ++i)
#pragma unroll
        for (int jn = 0; jn < 4; ++jn)
          acc[i][jn] = MFMA16(af[i], bfv[jn], acc[i][jn]);
    }
    __syncthreads();
  }

#pragma unroll
  for (int i = 0; i < 4; ++i) {
    int rbase = m0 + wr * 64 + i * 16 + (l >> 4) * 4;
#pragma unroll
    for (int jn = 0; jn < 4; ++jn) {
      int col = n0 + wc * 64 + jn * 16 + (l & 15);
      float bv = bias[col];
#pragma unroll
      for (int r = 0; r < 4; ++r)
        st1(&C[(size_t)(rbase + r) * N + col], acc[i][jn][r] + bv);
    }
  }
}

// ---------------------------------------------------------------------------
// FALLBACK GEMM (R6, reg-staged fp32/bf16 template) — used if ws too small.
// ---------------------------------------------------------------------------
template <typename AT, typename OT>
__global__ __launch_bounds__(256, 2) void gemm_bt_bias(
    const AT* __restrict__ A, const float* __restrict__ B,
    const float* __restrict__ bias, OT* __restrict__ C, int M, int N, int K) {
  __shared__ bf16 As[128][64];
  __shared__ bf16 Bs[128][64];

  const int tid = threadIdx.x;
  const int w = tid >> 6, l = tid & 63;
  const int wr = w >> 1, wc = w & 1;
  const int m0 = blockIdx.y * 128, n0 = blockIdx.x * 128;

  f32x4 acc[4][4] = {};

  const int srow = tid >> 3;
  const int scol = (tid & 7) * 8;

  for (int kt = 0; kt < K; kt += 64) {
    short8 aReg[4], bReg[4];
#pragma unroll
    for (int p = 0; p < 4; ++p) {
      int row = p * 32 + srow;
      aReg[p] = ld8bf(A + (size_t)(m0 + row) * K + kt + scol);
      bReg[p] = ld8bf(B + (size_t)(n0 + row) * K + kt + scol);
    }
    __syncthreads();
#pragma unroll
    for (int p = 0; p < 4; ++p) {
      int row = p * 32 + srow;
      *(short8*)&As[row][scol] = aReg[p];
      *(short8*)&Bs[row][scol] = bReg[p];
    }
    __syncthreads();

#pragma unroll
    for (int kk = 0; kk < 2; ++kk) {
      short8 af[4], bfv[4];
#pragma unroll
      for (int i = 0; i < 4; ++i) {
        af[i]  = *(const short8*)&As[wr * 64 + i * 16 + (l & 15)]
                                   [kk * 32 + (l >> 4) * 8];
        bfv[i] = *(const short8*)&Bs[wc * 64 + i * 16 + (l & 15)]
                                   [kk * 32 + (l >> 4) * 8];
      }
#pragma unroll
      for (int i = 0; i < 4; ++i)
#pragma unroll
        for (int jn = 0; jn < 4; ++jn)
          acc[i][jn] = MFMA16(af[i], bfv[jn], acc[i][jn]);
    }
  }

#pragma unroll
  for (int i = 0; i < 4; ++i) {
    int rbase = m0 + wr * 64 + i * 16 + (l >> 4) * 4;
#pragma unroll
    for (int jn = 0; jn < 4; ++jn) {
      int col = n0 + wc * 64 + jn * 16 + (l & 15);
      float bv = bias[col];
#pragma unroll
      for (int r = 0; r < 4; ++r)
        st1(&C[(size_t)(rbase + r) * N + col], acc[i][jn][r] + bv);
    }
  }
}

// ---------------------------------------------------------------------------
// Flash attention, swapped-operand 32x32 MFMA form (R6 + setprio + defer-max).
// ---------------------------------------------------------------------------
__global__ __launch_bounds__(256, 2) void attn_fwd(
    const bf16* __restrict__ qkv, bf16* __restrict__ attended) {
  const int S = 2048, D3 = 3072, D = 1024;
  const int qt = blockIdx.x, bh = blockIdx.y;
  const int b = bh >> 4, h = bh & 15;
  const int tid = threadIdx.x, w = tid >> 6, l = tid & 63;
  const int lo5 = l & 31, hi = l >> 5;

  __shared__ bf16 Klds[64][72];  // K[kv][e]
  __shared__ bf16 Vt[64][72];    // V^T[e][kv]

  const int q0w = qt * 128 + w * 32;

  short8 qf[4];
  {
    size_t qrow = (size_t)(b * S + q0w + lo5) * D3 + h * 64;
#pragma unroll
    for (int ks = 0; ks < 4; ++ks)
      qf[ks] = *(const short8*)&qkv[qrow + ks * 16 + hi * 8];
  }

  float m_raw = -1e30f, l_i = 0.f;
  f32x16 o0 = {}, o1 = {};

  const float Cs = 0.125f * 1.44269504088896340736f;  // hd^-0.5 * log2(e)

  const int srow = tid >> 2;
  const int scq = tid & 3;

  short8 k0, k1, v0, v1;
  {
    size_t gb = (size_t)(b * S + srow) * D3 + h * 64 + scq * 16;
    k0 = *(const short8*)&qkv[gb + 1024];
    k1 = *(const short8*)&qkv[gb + 1024 + 8];
    v0 = *(const short8*)&qkv[gb + 2048];
    v1 = *(const short8*)&qkv[gb + 2048 + 8];
  }

  for (int kv0 = 0; kv0 < S; kv0 += 64) {
    __syncthreads();  // WAR
    *(short8*)&Klds[srow][scq * 16] = k0;
    *(short8*)&Klds[srow][scq * 16 + 8] = k1;
#pragma unroll
    for (int g = 0; g < 2; ++g) {
      int sI = scq * 2 + g;
      short8 u = rotl8(g ? v1 : v0, sI);
#pragma unroll
      for (int j = 0; j < 8; ++j) {
        int jj = (j + sI) & 7;
        *(short*)&Vt[sI * 8 + jj][srow] = (short)u[j];
      }
    }
    __syncthreads();

    // prefetch next tile during compute (T14)
    if (kv0 + 64 < S) {
      size_t gb = (size_t)(b * S + kv0 + 64 + srow) * D3 + h * 64 + scq * 16;
      k0 = *(const short8*)&qkv[gb + 1024];
      k1 = *(const short8*)&qkv[gb + 1024 + 8];
      v0 = *(const short8*)&qkv[gb + 2048];
      v1 = *(const short8*)&qkv[gb + 2048 + 8];
    }

    // S^T = K @ Q^T
    f32x16 s0 = {}, s1 = {};
    __builtin_amdgcn_s_setprio(1);
#pragma unroll
    for (int ks = 0; ks < 4; ++ks) {
      short8 ka0 = *(const short8*)&Klds[lo5][ks * 16 + hi * 8];
      short8 ka1 = *(const short8*)&Klds[32 + lo5][ks * 16 + hi * 8];
      s0 = MFMA32(ka0, qf[ks], s0);
      s1 = MFMA32(ka1, qf[ks], s1);
    }
    __builtin_amdgcn_s_setprio(0);

    // per-lane online softmax with defer-max (T13, THR=8 in exp2-domain)
    f32x16 tm;
#pragma unroll
    for (int r = 0; r < 16; ++r) tm[r] = fmaxf(s0[r], s1[r]);
#pragma unroll
    for (int st = 8; st > 0; st >>= 1)
#pragma unroll
      for (int r = 0; r < st; ++r) tm[r] = fmaxf(tm[r], tm[r + st]);
    float mx = fmaxf(tm[0], __shfl_xor(tm[0], 32));

    bool deferred = __all((mx - m_raw) * Cs <= 8.0f);
    float mn, alpha;
    if (deferred) {
      mn = m_raw;           // keep old max; P bounded by 2^8, bf16-safe
      alpha = 1.0f;
    } else {
      mn = fmaxf(m_raw, mx);
      alpha = __builtin_amdgcn_exp2f((m_raw - mn) * Cs);
      m_raw = mn;
    }
    float pc = mn * Cs;

    f32x16 e0, e1;
#pragma unroll
    for (int r = 0; r < 16; ++r) {
      e0[r] = __builtin_amdgcn_exp2f(__builtin_fmaf(s0[r], Cs, -pc));
      e1[r] = __builtin_amdgcn_exp2f(__builtin_fmaf(s1[r], Cs, -pc));
    }
    f32x16 ts;
#pragma unroll
    for (int r = 0; r < 16; ++r) ts[r] = e0[r] + e1[r];
#pragma unroll
    for (int st = 8; st > 0; st >>= 1)
#pragma unroll
      for (int r = 0; r < st; ++r) ts[r] += ts[r + st];
    float sf = ts[0] + __shfl_xor(ts[0], 32);
    if (deferred) {
      l_i += sf;
    } else {
      l_i = l_i * alpha + sf;
      o0 *= alpha;
      o1 *= alpha;
    }

    // pack P quads + partner-lane exchange (1 shfl per u32 pair)
    unsigned po[2][4][2];
#pragma unroll
    for (int t = 0; t < 4; ++t) {
      po[0][t][0] = pk2(e0[4 * t], e0[4 * t + 1]);
      po[0][t][1] = pk2(e0[4 * t + 2], e0[4 * t + 3]);
      po[1][t][0] = pk2(e1[4 * t], e1[4 * t + 1]);
      po[1][t][1] = pk2(e1[4 * t + 2], e1[4 * t + 3]);
    }
    unsigned pr[2][2][2];
#pragma unroll
    for (int g = 0; g < 2; ++g)
#pragma unroll
      for (int p = 0; p < 2; ++p)
#pragma unroll
        for (int hf = 0; hf < 2; ++hf) {
          unsigned y = hi ? po[g][2 * p][hf] : po[g][2 * p + 1][hf];
          pr[g][p][hf] = (unsigned)__shfl_xor((int)y, 32);
        }

    // O^T += V^T @ P^T
    __builtin_amdgcn_s_setprio(1);
#pragma unroll
    for (int ks = 0; ks < 4; ++ks) {
      const int g = ks >> 1, p = ks & 1;
      u32x4 fw;
      fw[0] = hi ? pr[g][p][0] : po[g][2 * p][0];
      fw[1] = hi ? pr[g][p][1] : po[g][2 * p][1];
      fw[2] = hi ? po[g][2 * p + 1][0] : pr[g][p][0];
      fw[3] = hi ? po[g][2 * p + 1][1] : pr[g][p][1];
      short8 pf = __builtin_bit_cast(short8, fw);
      short8 va0 = *(const short8*)&Vt[lo5][ks * 16 + hi * 8];
      short8 va1 = *(const short8*)&Vt[32 + lo5][ks * 16 + hi * 8];
      o0 = MFMA32(va0, pf, o0);
      o1 = MFMA32(va1, pf, o1);
    }
    __builtin_amdgcn_s_setprio(0);
  }

  float inv = 1.0f / l_i;
  size_t orow = (size_t)(b * S + q0w + lo5) * D + h * 64;
#pragma unroll
  for (int t = 0; t < 4; ++t) {
    u32x2 w0, w1;
    w0[0] = pk2(o0[4 * t] * inv, o0[4 * t + 1] * inv);
    w0[1] = pk2(o0[4 * t + 2] * inv, o0[4 * t + 3] * inv);
    w1[0] = pk2(o1[4 * t] * inv, o1[4 * t + 1] * inv);
    w1[1] = pk2(o1[4 * t + 2] * inv, o1[4 * t + 3] * inv);
    *(u32x2*)&attended[orow + 8 * t + 4 * hi] = w0;
    *(u32x2*)&attended[orow + 32 + 8 * t + 4 * hi] = w1;
  }
}

// ---------------------------------------------------------------------------
extern "C" void kernel_launch(void* const* d_in, const int* in_sizes, int n_in,
                              void* d_out, int out_size, void* d_ws,
                              size_t ws_size, hipStream_t stream) {
  const float* x     = (const float*)d_in[0];   // [2,2048,1024] fp32
  const float* w_qkv = (const float*)d_in[1];   // [3072,1024]   fp32
  const float* b_qkv = (const float*)d_in[2];   // [3072]        fp32
  const float* w_out = (const float*)d_in[3];   // [1024,1024]   fp32
  const float* b_out = (const float*)d_in[4];   // [1024]        fp32
  float* out = (float*)d_out;                   // [2,2048,1024] fp32

  const int BS = 4096;   // B*S
  const int D = 1024, D3 = 3072;
  const int NX = BS * D, NWQ = D3 * D, NWO = D * D;

  bf16* qkv = (bf16*)d_ws;                       // [4096][3072] 25.2 MB
  bf16* att = qkv + (size_t)BS * D3;             // [4096][1024]  8.4 MB

  // fast path needs: qkv(25.2) + xb(8.4) + wqb(6.3) + wob(2.1) = 42 MB;
  // att overlays xb (x_bf16 dead after QKV GEMM).
  const size_t NEED = ((size_t)BS * D3 + (size_t)BS * D + (size_t)D3 * D +
                       (size_t)D * D) * sizeof(bf16);

  if (ws_size >= NEED) {
    bf16* xb  = att;                             // overlaid with att
    bf16* wqb = xb + (size_t)NX;
    bf16* wob = wqb + (size_t)NWQ;

    int ncvt = (NX + NWQ + NWO) / 8;             // 8 elems/thread
    cvt3<<<(ncvt + 255) / 256, 256, 0, stream>>>(x, xb, NX, w_qkv, wqb, NWQ,
                                                 w_out, wob, NWO);
    gemm_lds_bias<bf16><<<dim3(D3 / 128, BS / 128), 256, 0, stream>>>(
        xb, wqb, b_qkv, qkv, BS, D3, D);
    attn_fwd<<<dim3(16, 32), 256, 0, stream>>>(qkv, att);  // clobbers xb/wqb
    gemm_lds_bias<float><<<dim3(D / 128, BS / 128), 256, 0, stream>>>(
        att, wob, b_out, out, BS, D, D);
  } else {
    gemm_bt_bias<float, bf16><<<dim3(D3 / 128, BS / 128), 256, 0, stream>>>(
        x, w_qkv, b_qkv, qkv, BS, D3, D);
    attn_fwd<<<dim3(16, 32), 256, 0, stream>>>(qkv, att);
    gemm_bt_bias<bf16, float><<<dim3(D / 128, BS / 128), 256, 0, stream>>>(
        att, w_out, b_out, out, BS, D, D);
  }
}